// Round 2
// baseline (301.931 us; speedup 1.0000x reference)
//
#include <hip/hip_runtime.h>
#include <hip/hip_bf16.h>

// y = BlockDiag(blocks) @ x + U V^T x, * alpha + bias
// B=4 S=2048 D=4096 NB=16 (bi=bo=256) R=64 -> 8192 rows.
// prep: Bmat bf16 [4096][320] = [blocks(o)| U(o)] ; VT bf16 [64][4096]
// k1:   tpart[kc] = x[:, kc*1024 : +1024] @ V   (bf16 MFMA, direct-from-global frags)
// k1b:  tfin = sum_kc tpart
// k2:   out = GEMM(A=[x block-slice | tfin], B=Bmat, K=320) * alpha + bias

typedef __attribute__((ext_vector_type(8))) short short8;
typedef __attribute__((ext_vector_type(4))) float f32x4;

#define DIN 4096
#define DOUT 4096
#define KCAT 320

static __device__ __forceinline__ short f2bf(float f) {
  return __builtin_bit_cast(short, __float2bfloat16(f));
}
static __device__ __forceinline__ unsigned short f2bfu(float f) {
  return __builtin_bit_cast(unsigned short, __float2bfloat16(f));
}
static __device__ __forceinline__ short8 pack8(f32x4 a, f32x4 b) {
  short8 r;
  r[0] = f2bf(a[0]); r[1] = f2bf(a[1]); r[2] = f2bf(a[2]); r[3] = f2bf(a[3]);
  r[4] = f2bf(b[0]); r[5] = f2bf(b[1]); r[6] = f2bf(b[2]); r[7] = f2bf(b[3]);
  return r;
}
static __device__ __forceinline__ void gload_lds16(const void* g, void* l) {
  __builtin_amdgcn_global_load_lds(
      (const __attribute__((address_space(1))) unsigned int*)g,
      (__attribute__((address_space(3))) unsigned int*)l, 16, 0, 0);
}

// ---------------- prep: Bmat + V^T (bf16) ----------------
__global__ __launch_bounds__(256) void prep_kernel(
    const float* __restrict__ blocks, const float* __restrict__ U,
    const float* __restrict__ V, unsigned short* __restrict__ Bmat,
    unsigned short* __restrict__ VT) {
  int g = blockIdx.x * 256 + threadIdx.x;
  const int total1 = DOUT * KCAT;  // 1310720
  if (g < total1) {
    int o = g / KCAT;
    int k = g - o * KCAT;
    float v;
    if (k < 256)
      v = blocks[((o >> 8) << 16) | ((o & 255) << 8) | k];  // blocks[b][o%256][k]
    else
      v = U[o * 64 + (k - 256)];
    Bmat[g] = f2bfu(v);
  } else {
    int g2 = g - total1;
    if (g2 < 64 * DIN) {
      int r = g2 >> 12;
      int i = g2 & (DIN - 1);
      VT[g2] = f2bfu(V[i * 64 + r]);  // VT[r][i] = V[i][r]
    }
  }
}

// ---------------- k1: t-partials = x @ V ----------------
__global__ __launch_bounds__(256) void k1_xv(const float* __restrict__ x,
                                             const unsigned short* __restrict__ VT,
                                             float* __restrict__ tpart, int nrows) {
  const int rt = blockIdx.x >> 2;
  const int kc = blockIdx.x & 3;
  const int tid = threadIdx.x;
  const int w = tid >> 6, l = tid & 63;
  const int r0 = rt * 64 + w * 16;
  const int ko = (l >> 4) << 3;  // k sub-offset 0,8,16,24
  f32x4 acc[4];
#pragma unroll
  for (int i = 0; i < 4; ++i) acc[i] = (f32x4){0.f, 0.f, 0.f, 0.f};
  const float* xp = x + (size_t)(r0 + (l & 15)) * DIN + kc * 1024 + ko;
  const unsigned short* vp[4];
#pragma unroll
  for (int ct = 0; ct < 4; ++ct)
    vp[ct] = VT + (size_t)(ct * 16 + (l & 15)) * DIN + kc * 1024 + ko;
#pragma unroll 4
  for (int k = 0; k < 1024; k += 32) {
    f32x4 v0 = *(const f32x4*)(xp + k);
    f32x4 v1 = *(const f32x4*)(xp + k + 4);
    short8 af = pack8(v0, v1);
#pragma unroll
    for (int ct = 0; ct < 4; ++ct) {
      short8 bf = *(const short8*)(vp[ct] + k);
      acc[ct] = __builtin_amdgcn_mfma_f32_16x16x32_bf16(af, bf, acc[ct], 0, 0, 0);
    }
  }
  float* tp = tpart + (size_t)kc * nrows * 64;
  const int orow = r0 + ((l >> 4) << 2);
  const int ocol = l & 15;
#pragma unroll
  for (int ct = 0; ct < 4; ++ct)
#pragma unroll
    for (int r = 0; r < 4; ++r)
      tp[(size_t)(orow + r) * 64 + ct * 16 + ocol] = acc[ct][r];
}

// ---------------- k1b: reduce partials ----------------
__global__ __launch_bounds__(256) void k1_reduce(const float* __restrict__ tpart,
                                                 float* __restrict__ tfin, int n4) {
  int i = blockIdx.x * 256 + threadIdx.x;
  if (i >= n4) return;
  const f32x4* p = (const f32x4*)tpart;
  f32x4 s = p[i] + p[i + n4] + p[i + 2 * n4] + p[i + 3 * n4];
  ((f32x4*)tfin)[i] = s;
}

// ---------------- k2: main fused GEMM ----------------
// 128x128 tile, BK=64, K=320 (4 steps from x-slice, 1 from tfin), 4 waves 2x2.
// A tile fp32 [128][64] in LDS (32KB) staged via global_load_lds with XOR source
// swizzle: within a 256B row, 32B chunk c holds src chunk c^(row&7), 16B half h
// holds src half h^(row>>3&1)  -> bank-uniform ds_read_b128 on fragment reads.
// B tile bf16 [128][64] (16KB), 16B unit u holds src k-chunk u^(n&7).
__global__ __launch_bounds__(256, 3) void k2_main(
    const float* __restrict__ x, const float* __restrict__ tfin,
    const unsigned short* __restrict__ Bmat, const float* __restrict__ bias,
    const float* __restrict__ alphap, float* __restrict__ out, int nrt) {
  __shared__ __align__(1024) float ldsA[128 * 64];
  __shared__ __align__(1024) unsigned short ldsB[128 * 64];
  const int NCT = DOUT / 128;  // 32
  const int nwg = nrt * NCT;
  const int cpx = nwg >> 3;  // bijective chunked XCD swizzle (nwg % 8 == 0)
  const int id = blockIdx.x;
  const int sw = (id & 7) * cpx + (id >> 3);
  const int rt = sw / NCT;
  const int ct = sw - rt * NCT;
  const int row0 = rt * 128, col0 = ct * 128;
  const int b = ct >> 1;
  const int tid = threadIdx.x;
  const int w = tid >> 6, l = tid & 63;
  const int wm = w >> 1, wn = w & 1;

  int offX[8], offT[8];
#pragma unroll
  for (int r2 = 0; r2 < 8; ++r2) {
    int seg = r2 * 4 + w;
    int row = seg * 4 + (l >> 4);
    int chunk = (l & 15) >> 1;
    int half = l & 1;
    int col = (((chunk ^ (row & 7)) << 3) | (((half ^ (row >> 3)) & 1) << 2));
    offX[r2] = row * DIN + col;
    offT[r2] = row * 64 + col;
  }
  size_t offB[4];
#pragma unroll
  for (int r2 = 0; r2 < 4; ++r2) {
    int seg = r2 * 4 + w;
    int n = seg * 8 + (l >> 3);
    int kk = ((l & 7) ^ (n & 7)) << 3;
    offB[r2] = (size_t)(col0 + n) * KCAT + kk;
  }
  const float* xbase = x + (size_t)row0 * DIN + b * 256;
  const float* tbase = tfin + (size_t)row0 * 64;

  f32x4 acc[4][4];
#pragma unroll
  for (int mi = 0; mi < 4; ++mi)
#pragma unroll
    for (int ni = 0; ni < 4; ++ni) acc[mi][ni] = (f32x4){0.f, 0.f, 0.f, 0.f};

  char* ldsAb = (char*)ldsA;
  char* ldsBb = (char*)ldsB;
#pragma unroll
  for (int step = 0; step < 5; ++step) {
#pragma unroll
    for (int r2 = 0; r2 < 8; ++r2) {
      const float* src = (step < 4) ? (xbase + step * 64 + offX[r2]) : (tbase + offT[r2]);
      gload_lds16(src, ldsAb + (r2 * 4 + w) * 1024);
    }
#pragma unroll
    for (int r2 = 0; r2 < 4; ++r2)
      gload_lds16(Bmat + offB[r2] + step * 64, ldsBb + (r2 * 4 + w) * 1024);
    asm volatile("s_waitcnt vmcnt(0)" ::: "memory");
    __syncthreads();
#pragma unroll
    for (int ks = 0; ks < 2; ++ks) {
      short8 af[4], bfr[4];
#pragma unroll
      for (int mi = 0; mi < 4; ++mi) {
        int row = wm * 64 + mi * 16 + (l & 15);
        int kc2 = ks * 4 + (l >> 4);
        int off = row * 256 + (((kc2 ^ (row & 7)) << 5) | (((row >> 3) & 1) << 4));
        f32x4 v0 = *(const f32x4*)(ldsAb + off);
        f32x4 v1 = *(const f32x4*)(ldsAb + (off ^ 16));
        af[mi] = pack8(v0, v1);
      }
#pragma unroll
      for (int ni = 0; ni < 4; ++ni) {
        int n = wn * 64 + ni * 16 + (l & 15);
        int kc2 = ks * 4 + (l >> 4);
        int off = n * 128 + ((kc2 ^ (n & 7)) << 4);
        bfr[ni] = *(const short8*)(ldsBb + off);
      }
#pragma unroll
      for (int mi = 0; mi < 4; ++mi)
#pragma unroll
        for (int ni = 0; ni < 4; ++ni)
          acc[mi][ni] =
              __builtin_amdgcn_mfma_f32_16x16x32_bf16(af[mi], bfr[ni], acc[mi][ni], 0, 0, 0);
    }
    __syncthreads();
  }
  const float alpha = alphap[0];
#pragma unroll
  for (int ni = 0; ni < 4; ++ni) {
    int col = col0 + wn * 64 + ni * 16 + (l & 15);
    float bs = bias[col];
#pragma unroll
    for (int mi = 0; mi < 4; ++mi) {
      int rbase = row0 + wm * 64 + mi * 16 + ((l >> 4) << 2);
#pragma unroll
      for (int r = 0; r < 4; ++r)
        out[(size_t)(rbase + r) * DOUT + col] = acc[mi][ni][r] * alpha + bs;
    }
  }
}

extern "C" void kernel_launch(void* const* d_in, const int* in_sizes, int n_in,
                              void* d_out, int out_size, void* d_ws, size_t ws_size,
                              hipStream_t stream) {
  const float* x      = (const float*)d_in[0];
  const float* blocks = (const float*)d_in[1];
  const float* U      = (const float*)d_in[2];
  const float* V      = (const float*)d_in[3];
  const float* bias   = (const float*)d_in[4];
  const float* alpha  = (const float*)d_in[5];
  float* out = (float*)d_out;
  const int nrows = in_sizes[0] / DIN;  // 8192

  char* ws = (char*)d_ws;
  float* tpart = (float*)ws;                                     // 4 * nrows*64 f32
  float* tfin  = (float*)(ws + (size_t)4 * nrows * 64 * 4);      // nrows*64 f32
  unsigned short* Bmat =
      (unsigned short*)(ws + (size_t)5 * nrows * 64 * 4);        // 4096*320 bf16
  unsigned short* VT =
      (unsigned short*)(ws + (size_t)5 * nrows * 64 * 4 + (size_t)DOUT * KCAT * 2);

  const int prep_blocks = (DOUT * KCAT + 64 * DIN + 255) / 256;  // 6144
  prep_kernel<<<prep_blocks, 256, 0, stream>>>(blocks, U, V, Bmat, VT);
  k1_xv<<<(nrows / 64) * 4, 256, 0, stream>>>(x, VT, tpart, nrows);
  k1_reduce<<<(nrows * 64 / 4 + 255) / 256, 256, 0, stream>>>(tpart, tfin, nrows * 64 / 4);
  k2_main<<<(nrows / 128) * (DOUT / 128), 256, 0, stream>>>(x, tfin, Bmat, bias, alpha, out,
                                                            nrows / 128);
}